// Round 1
// baseline (7398.918 us; speedup 1.0000x reference)
//
#include <hip/hip_runtime.h>
#include <hip/hip_bf16.h>

#define LMAX 13.982028007507324f
#define LMIN -11.172813415527344f

// ---------------------------------------------------------------------------
// NDCG via bucketed ranking.
//  bucket_out: monotone-descending bucket of a float32 score (sortable-uint).
//  bucket_lab: descending bucket of a label in [0,1).
// ---------------------------------------------------------------------------

__device__ __forceinline__ unsigned bucket_out(float x, int logk) {
    unsigned u = __float_as_uint(x);
    // ascending sortable key
    unsigned key = u ^ ((u >> 31) ? 0xFFFFFFFFu : 0x80000000u);
    // descending bucket: largest value -> bucket 0
    return (~key) >> (32 - logk);
}

__device__ __forceinline__ unsigned bucket_lab(float l, unsigned K, float Kf) {
    unsigned u = (unsigned)(l * Kf);
    if (u > K - 1u) u = K - 1u;
    return (K - 1u) - u;   // highest label -> bucket 0
}

extern "C" __global__ void ndcg_hist(const float* __restrict__ sc,
                                     const float* __restrict__ lb,
                                     unsigned* __restrict__ c1,
                                     unsigned* __restrict__ c2,
                                     int n4, int logk, unsigned K, float Kf) {
    int stride = gridDim.x * blockDim.x;
    for (int i = blockIdx.x * blockDim.x + threadIdx.x; i < n4; i += stride) {
        float4 s = reinterpret_cast<const float4*>(sc)[i];
        float4 l = reinterpret_cast<const float4*>(lb)[i];
        atomicAdd(&c1[bucket_out(s.x, logk)], 1u);
        atomicAdd(&c1[bucket_out(s.y, logk)], 1u);
        atomicAdd(&c1[bucket_out(s.z, logk)], 1u);
        atomicAdd(&c1[bucket_out(s.w, logk)], 1u);
        atomicAdd(&c2[bucket_lab(l.x, K, Kf)], 1u);
        atomicAdd(&c2[bucket_lab(l.y, K, Kf)], 1u);
        atomicAdd(&c2[bucket_lab(l.z, K, Kf)], 1u);
        atomicAdd(&c2[bucket_lab(l.w, K, Kf)], 1u);
    }
}

// Single-block exclusive scan of K (power of 2, >=1024) counters.
extern "C" __global__ void ndcg_scan(const unsigned* __restrict__ in,
                                     unsigned* __restrict__ out, unsigned K) {
    __shared__ unsigned sums[1024];
    const int t = threadIdx.x;
    const int chunk = (int)(K >> 10);
    const int base = t * chunk;
    unsigned s = 0;
    for (int j = 0; j < chunk; ++j) s += in[base + j];
    sums[t] = s;
    __syncthreads();
    // Hillis-Steele inclusive scan over 1024 partials
    for (int off = 1; off < 1024; off <<= 1) {
        unsigned v = (t >= off) ? sums[t - off] : 0u;
        __syncthreads();
        sums[t] += v;
        __syncthreads();
    }
    unsigned run = (t == 0) ? 0u : sums[t - 1];
    for (int j = 0; j < chunk; ++j) {
        unsigned v = in[base + j];
        out[base + j] = run;   // exclusive prefix = base rank of bucket
        run += v;
    }
}

__device__ __forceinline__ double wave_sum(double v) {
    for (int off = 32; off > 0; off >>= 1) v += __shfl_down(v, off, 64);
    return v;
}

extern "C" __global__ void ndcg_main(const float* __restrict__ sc,
                                     const float* __restrict__ lb,
                                     unsigned* __restrict__ p1,
                                     unsigned* __restrict__ p2,
                                     double* __restrict__ acc,
                                     int n4, int logk, unsigned K, float Kf) {
    double ld = 0.0, lz = 0.0;
    int stride = gridDim.x * blockDim.x;
    for (int i = blockIdx.x * blockDim.x + threadIdx.x; i < n4; i += stride) {
        float4 s = reinterpret_cast<const float4*>(sc)[i];
        float4 l = reinterpret_cast<const float4*>(lb)[i];
        float ss[4] = {s.x, s.y, s.z, s.w};
        float ll[4] = {l.x, l.y, l.z, l.w};
#pragma unroll
        for (int j = 0; j < 4; ++j) {
            float gain = exp2f(ll[j] * (LMAX - LMIN) + LMIN) - 1.0f;
            unsigned r1 = atomicAdd(&p1[bucket_out(ss[j], logk)], 1u);
            unsigned r2 = atomicAdd(&p2[bucket_lab(ll[j], K, Kf)], 1u);
            float d1 = 1.0f / log2f((float)(r1 + 2u));
            float d2 = 1.0f / log2f((float)(r2 + 2u));
            ld += (double)(gain * d1);
            lz += (double)(gain * d2);
        }
    }
    // block reduction: wave shuffle -> LDS -> 2 global f64 atomics per block
    __shared__ double sd[2][4];
    int wid = threadIdx.x >> 6, lane = threadIdx.x & 63;
    ld = wave_sum(ld);
    lz = wave_sum(lz);
    if (lane == 0) { sd[0][wid] = ld; sd[1][wid] = lz; }
    __syncthreads();
    if (threadIdx.x == 0) {
        double a = sd[0][0] + sd[0][1] + sd[0][2] + sd[0][3];
        double b = sd[1][0] + sd[1][1] + sd[1][2] + sd[1][3];
        atomicAdd(&acc[0], a);
        atomicAdd(&acc[1], b);
    }
}

extern "C" __global__ void ndcg_fin(const double* __restrict__ acc,
                                    float* __restrict__ out) {
    if (threadIdx.x == 0 && blockIdx.x == 0) out[0] = (float)(acc[0] / acc[1]);
}

extern "C" void kernel_launch(void* const* d_in, const int* in_sizes, int n_in,
                              void* d_out, int out_size, void* d_ws, size_t ws_size,
                              hipStream_t stream) {
    const float* sc = (const float*)d_in[0];
    const float* lb = (const float*)d_in[1];
    int n = in_sizes[0];

    // bucket count: 2^17 if workspace allows (needs 16 + 16*K bytes), else shrink
    int logk = 17;
    while (logk > 10 && (size_t)16 + ((size_t)16 << logk) > ws_size) --logk;
    unsigned K = 1u << logk;

    char* base = (char*)d_ws;
    double* acc = (double*)base;                    // [0]=dcg, [1]=zk
    unsigned* c1 = (unsigned*)(base + 16);          // score-bucket counts
    unsigned* c2 = c1 + K;                          // label-bucket counts
    unsigned* p1 = c2 + K;                          // score-bucket base ranks (then cursors)
    unsigned* p2 = p1 + K;                          // label-bucket base ranks (then cursors)

    // zero acc + both count tables each call (graph-replay safe)
    hipMemsetAsync(d_ws, 0, (size_t)16 + ((size_t)8 << logk), stream);

    int n4 = n / 4;
    dim3 blk(256), grd(2048);
    ndcg_hist<<<grd, blk, 0, stream>>>(sc, lb, c1, c2, n4, logk, K, (float)K);
    ndcg_scan<<<1, 1024, 0, stream>>>(c1, p1, K);
    ndcg_scan<<<1, 1024, 0, stream>>>(c2, p2, K);
    ndcg_main<<<grd, blk, 0, stream>>>(sc, lb, p1, p2, acc, n4, logk, K, (float)K);
    ndcg_fin<<<1, 64, 0, stream>>>(acc, (float*)d_out);
}

// Round 2
// 629.053 us; speedup vs baseline: 11.7620x; 11.7620x over previous
//
#include <hip/hip_runtime.h>
#include <hip/hip_bf16.h>

#define LOGK 13
#define K 8192
#define LMINF  -11.172813415527344f
#define RANGEF  25.154841423034668f   // LABEL_MAX - LABEL_MIN

// descending bucket of a float32 score via sortable-uint top bits
__device__ __forceinline__ unsigned bucket_out(float x) {
    unsigned u = __float_as_uint(x);
    unsigned key = u ^ ((u >> 31) ? 0xFFFFFFFFu : 0x80000000u);
    return (~key) >> (32 - LOGK);
}
// descending bucket of a label in [0,1)
__device__ __forceinline__ unsigned bucket_lab(float l) {
    unsigned u = (unsigned)(l * (float)K);
    if (u > (unsigned)(K - 1)) u = K - 1;
    return (unsigned)(K - 1) - u;
}

// ---------------------------------------------------------------------------
// P1: LDS-privatized histograms. Blocks [0,nb) build the score histogram,
// blocks [nb,2nb) the label histogram. Per-block tables -> ws.
// Layout: ptc/ptg are [2][nb][K].
// ---------------------------------------------------------------------------
extern "C" __global__ __launch_bounds__(1024)
void ndcg_hist2(const float* __restrict__ sc, const float* __restrict__ lb,
                unsigned* __restrict__ ptc, float* __restrict__ ptg,
                int n4, int nb) {
    __shared__ unsigned cnt[K];
    __shared__ float    gs[K];
    const int bid  = blockIdx.x;
    const int role = (bid >= nb) ? 1 : 0;
    const int rb   = role ? bid - nb : bid;
    for (int c = threadIdx.x; c < K; c += 1024) { cnt[c] = 0u; gs[c] = 0.f; }
    __syncthreads();
    const int start = rb * 1024 + threadIdx.x;
    const int step  = nb * 1024;
    if (role == 0) {
        for (int i = start; i < n4; i += step) {
            float4 s = reinterpret_cast<const float4*>(sc)[i];
            float4 l = reinterpret_cast<const float4*>(lb)[i];
            float ss[4] = {s.x, s.y, s.z, s.w};
            float ll[4] = {l.x, l.y, l.z, l.w};
#pragma unroll
            for (int j = 0; j < 4; ++j) {
                float g = exp2f(fmaf(ll[j], RANGEF, LMINF)) - 1.0f;
                unsigned b = bucket_out(ss[j]);
                atomicAdd(&cnt[b], 1u);
                atomicAdd(&gs[b], g);
            }
        }
    } else {
        for (int i = start; i < n4; i += step) {
            float4 l = reinterpret_cast<const float4*>(lb)[i];
            float ll[4] = {l.x, l.y, l.z, l.w};
#pragma unroll
            for (int j = 0; j < 4; ++j) {
                float g = exp2f(fmaf(ll[j], RANGEF, LMINF)) - 1.0f;
                unsigned b = bucket_lab(ll[j]);
                atomicAdd(&cnt[b], 1u);
                atomicAdd(&gs[b], g);
            }
        }
    }
    __syncthreads();
    size_t row = ((size_t)role * nb + rb) * K;
    for (int c = threadIdx.x; c < K; c += 1024) {
        ptc[row + c] = cnt[c];
        ptg[row + c] = gs[c];
    }
}

// ---------------------------------------------------------------------------
// P2a: merge per-block tables (coalesced, no atomics).
// counts -> base{1,2}[c], gainsums -> gs{1,2}[c]
// ---------------------------------------------------------------------------
extern "C" __global__ void ndcg_reduce2(const unsigned* __restrict__ ptc,
                                        const float* __restrict__ ptg,
                                        unsigned* __restrict__ base1, float* __restrict__ gs1,
                                        unsigned* __restrict__ base2, float* __restrict__ gs2,
                                        int nb) {
    int t = blockIdx.x * blockDim.x + threadIdx.x;
    if (t >= 2 * K) return;
    int table = t >> LOGK;
    int c = t & (K - 1);
    size_t off = ((size_t)table * nb) * K + c;
    unsigned cs = 0u; float g = 0.f;
    for (int b = 0; b < nb; ++b) { cs += ptc[off]; g += ptg[off]; off += K; }
    if (table == 0) { base1[c] = cs; gs1[c] = g; }
    else            { base2[c] = cs; gs2[c] = g; }
}

// ---------------------------------------------------------------------------
// P2b: in-place exclusive scan of counts -> bucket base ranks, appends total
// at base[K]. blockIdx 0 -> base1, 1 -> base2.
// ---------------------------------------------------------------------------
extern "C" __global__ __launch_bounds__(1024)
void ndcg_scan2(unsigned* __restrict__ base1, unsigned* __restrict__ base2) {
    unsigned* base = blockIdx.x ? base2 : base1;
    __shared__ unsigned sums[1024];
    const int t = threadIdx.x;
    const int chunk = K / 1024;           // 8
    unsigned v[8];
    unsigned s = 0u;
#pragma unroll
    for (int j = 0; j < chunk; ++j) { v[j] = base[t * chunk + j]; s += v[j]; }
    sums[t] = s;
    __syncthreads();
    for (int off = 1; off < 1024; off <<= 1) {
        unsigned add = (t >= off) ? sums[t - off] : 0u;
        __syncthreads();
        sums[t] += add;
        __syncthreads();
    }
    unsigned run = (t == 0) ? 0u : sums[t - 1];
#pragma unroll
    for (int j = 0; j < chunk; ++j) { unsigned x = v[j]; base[t * chunk + j] = run; run += x; }
    if (t == 1023) base[K] = run;         // = n
}

// ---------------------------------------------------------------------------
// P3: rank-major walk. Thread owns C consecutive ranks; one binary search,
// then walk buckets. acc += disc(r) * bucket_avg_gain. No atomics per item.
// ---------------------------------------------------------------------------
__device__ __forceinline__ float walk_table(const unsigned* __restrict__ base,
                                            const float* __restrict__ gs,
                                            int r0, int r1) {
    unsigned lo = 0, hi = K;              // invariant: base[lo] <= r0 < base[hi]
    while (hi - lo > 1u) {
        unsigned mid = (lo + hi) >> 1;
        if (base[mid] <= (unsigned)r0) lo = mid; else hi = mid;
    }
    unsigned b = lo;
    unsigned e = base[b + 1];
    float avg = gs[b] / (float)(e - base[b]);
    float acc = 0.f;
    for (int r = r0; r < r1; ++r) {
        if ((unsigned)r >= e) {
            do { ++b; e = base[b + 1]; } while ((unsigned)r >= e);
            avg = gs[b] / (float)(e - base[b]);
        }
        acc += avg / log2f((float)(r + 2));
    }
    return acc;
}

extern "C" __global__ void ndcg_walk(const unsigned* __restrict__ base1, const float* __restrict__ gs1,
                                     const unsigned* __restrict__ base2, const float* __restrict__ gs2,
                                     double* __restrict__ acc, int n, int C) {
    int tid = blockIdx.x * blockDim.x + threadIdx.x;
    long r0l = (long)tid * C;
    double ld = 0.0, lz = 0.0;
    if (r0l < (long)n) {
        int r0 = (int)r0l;
        int r1 = min(n, r0 + C);
        ld = (double)walk_table(base1, gs1, r0, r1);
        lz = (double)walk_table(base2, gs2, r0, r1);
    }
    for (int off = 32; off > 0; off >>= 1) {
        ld += __shfl_down(ld, off, 64);
        lz += __shfl_down(lz, off, 64);
    }
    __shared__ double sd[2][4];
    int wid = threadIdx.x >> 6, lane = threadIdx.x & 63;
    if (lane == 0) { sd[0][wid] = ld; sd[1][wid] = lz; }
    __syncthreads();
    if (threadIdx.x == 0) {
        atomicAdd(&acc[0], sd[0][0] + sd[0][1] + sd[0][2] + sd[0][3]);
        atomicAdd(&acc[1], sd[1][0] + sd[1][1] + sd[1][2] + sd[1][3]);
    }
}

extern "C" __global__ void ndcg_fin(const double* __restrict__ acc,
                                    float* __restrict__ out) {
    if (threadIdx.x == 0 && blockIdx.x == 0) out[0] = (float)(acc[0] / acc[1]);
}

extern "C" void kernel_launch(void* const* d_in, const int* in_sizes, int n_in,
                              void* d_out, int out_size, void* d_ws, size_t ws_size,
                              hipStream_t stream) {
    const float* sc = (const float*)d_in[0];
    const float* lb = (const float*)d_in[1];
    int n = in_sizes[0];
    int n4 = n / 4;

    // workspace layout
    char* p = (char*)d_ws;
    size_t off = 0;
    double*   acc   = (double*)(p + off);   off += 256;
    unsigned* base1 = (unsigned*)(p + off); off += ((size_t)(K + 1) * 4 + 255) & ~(size_t)255;
    unsigned* base2 = (unsigned*)(p + off); off += ((size_t)(K + 1) * 4 + 255) & ~(size_t)255;
    float*    gs1   = (float*)(p + off);    off += (size_t)K * 4;
    float*    gs2   = (float*)(p + off);    off += (size_t)K * 4;
    size_t fixed = off;

    // nb blocks per histogram role; per-nb cost = 2 tables * K * (4+4) bytes
    size_t per_nb = (size_t)2 * K * 8;
    int nb = 256;
    if (fixed + (size_t)nb * per_nb > ws_size) {
        size_t avail = (ws_size > fixed) ? ws_size - fixed : 0;
        nb = (int)(avail / per_nb);
        if (nb < 1) nb = 1;
        if (nb > 256) nb = 256;
    }
    unsigned* ptc = (unsigned*)(p + fixed);                       // [2][nb][K] u32
    float*    ptg = (float*)(p + fixed + (size_t)2 * nb * K * 4); // [2][nb][K] f32

    hipMemsetAsync(acc, 0, 16, stream);

    ndcg_hist2<<<dim3(2 * nb), dim3(1024), 0, stream>>>(sc, lb, ptc, ptg, n4, nb);
    ndcg_reduce2<<<dim3((2 * K + 255) / 256), dim3(256), 0, stream>>>(ptc, ptg, base1, gs1, base2, gs2, nb);
    ndcg_scan2<<<dim3(2), dim3(1024), 0, stream>>>(base1, base2);

    const int T = 2048 * 256;
    int C = (n + T - 1) / T;
    ndcg_walk<<<dim3(2048), dim3(256), 0, stream>>>(base1, gs1, base2, gs2, acc, n, C);
    ndcg_fin<<<dim3(1), dim3(64), 0, stream>>>(acc, (float*)d_out);
}

// Round 3
// 362.458 us; speedup vs baseline: 20.4132x; 1.7355x over previous
//
#include <hip/hip_runtime.h>
#include <hip/hip_bf16.h>

#define LOGK 13
#define K 8192
#define LMINF  -11.172813415527344f
#define RANGEF  25.154841423034668f   // LABEL_MAX - LABEL_MIN

// descending bucket of a float32 score via sortable-uint top bits
__device__ __forceinline__ unsigned bucket_out(float x) {
    unsigned u = __float_as_uint(x);
    unsigned key = u ^ ((u >> 31) ? 0xFFFFFFFFu : 0x80000000u);
    return (~key) >> (32 - LOGK);
}
// descending bucket of a label in [0,1)
__device__ __forceinline__ unsigned bucket_lab(float l) {
    unsigned u = (unsigned)(l * (float)K);
    if (u > (unsigned)(K - 1)) u = K - 1;
    return (unsigned)(K - 1) - u;
}

// ---------------------------------------------------------------------------
// P1: LDS-privatized histograms. Blocks [0,nb) build the score histogram,
// blocks [nb,2nb) the label histogram. Per-block tables -> ws.
// Layout: ptc/ptg are [2][nb][K].
// ---------------------------------------------------------------------------
extern "C" __global__ __launch_bounds__(1024)
void ndcg_hist2(const float* __restrict__ sc, const float* __restrict__ lb,
                unsigned* __restrict__ ptc, float* __restrict__ ptg,
                int n4, int nb) {
    __shared__ unsigned cnt[K];
    __shared__ float    gs[K];
    const int bid  = blockIdx.x;
    const int role = (bid >= nb) ? 1 : 0;
    const int rb   = role ? bid - nb : bid;
    for (int c = threadIdx.x; c < K; c += 1024) { cnt[c] = 0u; gs[c] = 0.f; }
    __syncthreads();
    const int start = rb * 1024 + threadIdx.x;
    const int step  = nb * 1024;
    if (role == 0) {
        for (int i = start; i < n4; i += step) {
            float4 s = reinterpret_cast<const float4*>(sc)[i];
            float4 l = reinterpret_cast<const float4*>(lb)[i];
            float ss[4] = {s.x, s.y, s.z, s.w};
            float ll[4] = {l.x, l.y, l.z, l.w};
#pragma unroll
            for (int j = 0; j < 4; ++j) {
                float g = exp2f(fmaf(ll[j], RANGEF, LMINF)) - 1.0f;
                unsigned b = bucket_out(ss[j]);
                atomicAdd(&cnt[b], 1u);
                atomicAdd(&gs[b], g);
            }
        }
    } else {
        for (int i = start; i < n4; i += step) {
            float4 l = reinterpret_cast<const float4*>(lb)[i];
            float ll[4] = {l.x, l.y, l.z, l.w};
#pragma unroll
            for (int j = 0; j < 4; ++j) {
                float g = exp2f(fmaf(ll[j], RANGEF, LMINF)) - 1.0f;
                unsigned b = bucket_lab(ll[j]);
                atomicAdd(&cnt[b], 1u);
                atomicAdd(&gs[b], g);
            }
        }
    }
    __syncthreads();
    size_t row = ((size_t)role * nb + rb) * K;
    for (int c = threadIdx.x; c < K; c += 1024) {
        ptc[row + c] = cnt[c];
        ptg[row + c] = gs[c];
    }
}

// ---------------------------------------------------------------------------
// P2a: merge per-block tables (coalesced, no atomics).
// ---------------------------------------------------------------------------
extern "C" __global__ void ndcg_reduce2(const unsigned* __restrict__ ptc,
                                        const float* __restrict__ ptg,
                                        unsigned* __restrict__ base1, float* __restrict__ gs1,
                                        unsigned* __restrict__ base2, float* __restrict__ gs2,
                                        int nb) {
    int t = blockIdx.x * blockDim.x + threadIdx.x;
    if (t >= 2 * K) return;
    int table = t >> LOGK;
    int c = t & (K - 1);
    size_t off = ((size_t)table * nb) * K + c;
    unsigned cs = 0u; float g = 0.f;
    for (int b = 0; b < nb; ++b) { cs += ptc[off]; g += ptg[off]; off += K; }
    if (table == 0) { base1[c] = cs; gs1[c] = g; }
    else            { base2[c] = cs; gs2[c] = g; }
}

// ---------------------------------------------------------------------------
// P2b: in-place exclusive scan of counts -> bucket base ranks, appends total
// at base[K]. blockIdx 0 -> base1, 1 -> base2.
// ---------------------------------------------------------------------------
extern "C" __global__ __launch_bounds__(1024)
void ndcg_scan2(unsigned* __restrict__ base1, unsigned* __restrict__ base2) {
    unsigned* base = blockIdx.x ? base2 : base1;
    __shared__ unsigned sums[1024];
    const int t = threadIdx.x;
    const int chunk = K / 1024;           // 8
    unsigned v[8];
    unsigned s = 0u;
#pragma unroll
    for (int j = 0; j < chunk; ++j) { v[j] = base[t * chunk + j]; s += v[j]; }
    sums[t] = s;
    __syncthreads();
    for (int off = 1; off < 1024; off <<= 1) {
        unsigned add = (t >= off) ? sums[t - off] : 0u;
        __syncthreads();
        sums[t] += add;
        __syncthreads();
    }
    unsigned run = (t == 0) ? 0u : sums[t - 1];
#pragma unroll
    for (int j = 0; j < chunk; ++j) { unsigned x = v[j]; base[t * chunk + j] = run; run += x; }
    if (t == 1023) base[K] = run;         // = n
}

// ---------------------------------------------------------------------------
// P3: rank-major walk. Thread owns C consecutive ranks. Bucket advance is a
// BINARY SEARCH (not linear) — the score table has ~3800 consecutive empty
// buckets around score==0 (float-exponent desert); linear advance made one
// thread serially walk all of them (~360us tail in round 2).
// ---------------------------------------------------------------------------
__device__ __forceinline__ unsigned find_bucket(const unsigned* __restrict__ base,
                                                unsigned lo, unsigned hi, unsigned r) {
    // invariant: base[lo] <= r < base[hi]
    while (hi - lo > 1u) {
        unsigned mid = (lo + hi) >> 1;
        if (base[mid] <= r) lo = mid; else hi = mid;
    }
    return lo;
}

__device__ __forceinline__ float walk_table(const unsigned* __restrict__ base,
                                            const float* __restrict__ gs,
                                            int r0, int r1) {
    unsigned b = find_bucket(base, 0u, K, (unsigned)r0);
    unsigned e = base[b + 1];
    float avg = gs[b] / (float)(e - base[b]);
    float acc = 0.f;
    for (int r = r0; r < r1; ++r) {
        if ((unsigned)r >= e) {
            b = find_bucket(base, b + 1u, K, (unsigned)r);
            e = base[b + 1];
            avg = gs[b] / (float)(e - base[b]);
        }
        acc += avg / log2f((float)(r + 2));
    }
    return acc;
}

extern "C" __global__ void ndcg_walk(const unsigned* __restrict__ base1, const float* __restrict__ gs1,
                                     const unsigned* __restrict__ base2, const float* __restrict__ gs2,
                                     double* __restrict__ acc, int n, int C) {
    int tid = blockIdx.x * blockDim.x + threadIdx.x;
    long r0l = (long)tid * C;
    double ld = 0.0, lz = 0.0;
    if (r0l < (long)n) {
        int r0 = (int)r0l;
        int r1 = min(n, r0 + C);
        ld = (double)walk_table(base1, gs1, r0, r1);
        lz = (double)walk_table(base2, gs2, r0, r1);
    }
    for (int off = 32; off > 0; off >>= 1) {
        ld += __shfl_down(ld, off, 64);
        lz += __shfl_down(lz, off, 64);
    }
    __shared__ double sd[2][4];
    int wid = threadIdx.x >> 6, lane = threadIdx.x & 63;
    if (lane == 0) { sd[0][wid] = ld; sd[1][wid] = lz; }
    __syncthreads();
    if (threadIdx.x == 0) {
        atomicAdd(&acc[0], sd[0][0] + sd[0][1] + sd[0][2] + sd[0][3]);
        atomicAdd(&acc[1], sd[1][0] + sd[1][1] + sd[1][2] + sd[1][3]);
    }
}

extern "C" __global__ void ndcg_fin(const double* __restrict__ acc,
                                    float* __restrict__ out) {
    if (threadIdx.x == 0 && blockIdx.x == 0) out[0] = (float)(acc[0] / acc[1]);
}

extern "C" void kernel_launch(void* const* d_in, const int* in_sizes, int n_in,
                              void* d_out, int out_size, void* d_ws, size_t ws_size,
                              hipStream_t stream) {
    const float* sc = (const float*)d_in[0];
    const float* lb = (const float*)d_in[1];
    int n = in_sizes[0];
    int n4 = n / 4;

    // workspace layout
    char* p = (char*)d_ws;
    size_t off = 0;
    double*   acc   = (double*)(p + off);   off += 256;
    unsigned* base1 = (unsigned*)(p + off); off += ((size_t)(K + 1) * 4 + 255) & ~(size_t)255;
    unsigned* base2 = (unsigned*)(p + off); off += ((size_t)(K + 1) * 4 + 255) & ~(size_t)255;
    float*    gs1   = (float*)(p + off);    off += (size_t)K * 4;
    float*    gs2   = (float*)(p + off);    off += (size_t)K * 4;
    size_t fixed = off;

    size_t per_nb = (size_t)2 * K * 8;
    int nb = 256;
    if (fixed + (size_t)nb * per_nb > ws_size) {
        size_t avail = (ws_size > fixed) ? ws_size - fixed : 0;
        nb = (int)(avail / per_nb);
        if (nb < 1) nb = 1;
        if (nb > 256) nb = 256;
    }
    unsigned* ptc = (unsigned*)(p + fixed);
    float*    ptg = (float*)(p + fixed + (size_t)2 * nb * K * 4);

    hipMemsetAsync(acc, 0, 16, stream);

    ndcg_hist2<<<dim3(2 * nb), dim3(1024), 0, stream>>>(sc, lb, ptc, ptg, n4, nb);
    ndcg_reduce2<<<dim3((2 * K + 255) / 256), dim3(256), 0, stream>>>(ptc, ptg, base1, gs1, base2, gs2, nb);
    ndcg_scan2<<<dim3(2), dim3(1024), 0, stream>>>(base1, base2);

    const int T = 2048 * 256;
    int C = (n + T - 1) / T;
    ndcg_walk<<<dim3(2048), dim3(256), 0, stream>>>(base1, gs1, base2, gs2, acc, n, C);
    ndcg_fin<<<dim3(1), dim3(64), 0, stream>>>(acc, (float*)d_out);
}

// Round 4
// 188.363 us; speedup vs baseline: 39.2800x; 1.9242x over previous
//
#include <hip/hip_runtime.h>
#include <hip/hip_bf16.h>

#define LOGK 13
#define K 8192
#define LMINF  -11.172813415527344f
#define RANGEF  25.154841423034668f   // LABEL_MAX - LABEL_MIN
#define GSCALE 65536.0f               // fixed-point scale for (gain+1) in packed u64
#define GMASK  ((1ULL << 47) - 1)

// descending bucket of a float32 score via sortable-uint top bits
__device__ __forceinline__ unsigned bucket_out(float x) {
    unsigned u = __float_as_uint(x);
    unsigned key = u ^ ((u >> 31) ? 0xFFFFFFFFu : 0x80000000u);
    return (~key) >> (32 - LOGK);
}
// descending bucket of a label in [0,1)
__device__ __forceinline__ unsigned bucket_lab(float l) {
    unsigned u = (unsigned)(l * (float)K);
    if (u > (unsigned)(K - 1)) u = K - 1;
    return (unsigned)(K - 1) - u;
}

// ---------------------------------------------------------------------------
// P1: LDS-privatized histograms, batched loads for memory-level parallelism.
// role 0 (blocks [0,nb)):   score histogram; ONE packed u64 LDS atomic/item:
//                           [63:47]=count, [46:0]=(gain+1)*2^16 fixed point.
// role 1 (blocks [nb,2nb)): label histogram; counts only (u32 atomic) — the
//                           per-bucket mean gain is analytic (bucket width
//                           1/8192 -> gain varies by x1.002 within bucket).
// ---------------------------------------------------------------------------
extern "C" __global__ __launch_bounds__(1024)
void ndcg_hist3(const float* __restrict__ sc, const float* __restrict__ lb,
                unsigned long long* __restrict__ pt0, unsigned* __restrict__ pt1,
                int n4, int nb) {
    __shared__ unsigned long long pk[K];     // 64 KB; role 1 uses low 32 KB as u32
    const int bid  = blockIdx.x;
    const int role = (bid >= nb) ? 1 : 0;
    const int rb   = role ? bid - nb : bid;
    const int tid  = threadIdx.x;
    const float4* sc4 = (const float4*)sc;
    const float4* lb4 = (const float4*)lb;
    const int col = nb << 10;                // float4s per column

    if (role == 0) {
        for (int c = tid; c < K; c += 1024) pk[c] = 0ull;
        __syncthreads();
        for (int i = rb * 1024 + tid; i < n4; i += 2 * col) {
            float4 s0 = sc4[i];
            float4 l0 = lb4[i];
            int i1 = i + col;
            bool h1 = i1 < n4;
            float4 s1 = {}, l1 = {};
            if (h1) { s1 = sc4[i1]; l1 = lb4[i1]; }
            {
                float ss[4] = {s0.x, s0.y, s0.z, s0.w};
                float ll[4] = {l0.x, l0.y, l0.z, l0.w};
#pragma unroll
                for (int j = 0; j < 4; ++j) {
                    float h = exp2f(fmaf(ll[j], RANGEF, LMINF));      // gain+1 >= 0
                    unsigned gf = (unsigned)(h * GSCALE);
                    atomicAdd(&pk[bucket_out(ss[j])], (1ULL << 47) | (unsigned long long)gf);
                }
            }
            if (h1) {
                float ss[4] = {s1.x, s1.y, s1.z, s1.w};
                float ll[4] = {l1.x, l1.y, l1.z, l1.w};
#pragma unroll
                for (int j = 0; j < 4; ++j) {
                    float h = exp2f(fmaf(ll[j], RANGEF, LMINF));
                    unsigned gf = (unsigned)(h * GSCALE);
                    atomicAdd(&pk[bucket_out(ss[j])], (1ULL << 47) | (unsigned long long)gf);
                }
            }
        }
        __syncthreads();
        unsigned long long* dst = pt0 + (size_t)rb * K;
        for (int c = tid; c < K; c += 1024) dst[c] = pk[c];
    } else {
        unsigned* cnt = (unsigned*)pk;
        for (int c = tid; c < K; c += 1024) cnt[c] = 0u;
        __syncthreads();
        for (int i = rb * 1024 + tid; i < n4; i += 4 * col) {
            int i1 = i + col, i2 = i + 2 * col, i3 = i + 3 * col;
            bool h1 = i1 < n4, h2 = i2 < n4, h3 = i3 < n4;
            float4 l0 = lb4[i];
            float4 l1 = {}, l2 = {}, l3 = {};
            if (h1) l1 = lb4[i1];
            if (h2) l2 = lb4[i2];
            if (h3) l3 = lb4[i3];
            atomicAdd(&cnt[bucket_lab(l0.x)], 1u);
            atomicAdd(&cnt[bucket_lab(l0.y)], 1u);
            atomicAdd(&cnt[bucket_lab(l0.z)], 1u);
            atomicAdd(&cnt[bucket_lab(l0.w)], 1u);
            if (h1) {
                atomicAdd(&cnt[bucket_lab(l1.x)], 1u);
                atomicAdd(&cnt[bucket_lab(l1.y)], 1u);
                atomicAdd(&cnt[bucket_lab(l1.z)], 1u);
                atomicAdd(&cnt[bucket_lab(l1.w)], 1u);
            }
            if (h2) {
                atomicAdd(&cnt[bucket_lab(l2.x)], 1u);
                atomicAdd(&cnt[bucket_lab(l2.y)], 1u);
                atomicAdd(&cnt[bucket_lab(l2.z)], 1u);
                atomicAdd(&cnt[bucket_lab(l2.w)], 1u);
            }
            if (h3) {
                atomicAdd(&cnt[bucket_lab(l3.x)], 1u);
                atomicAdd(&cnt[bucket_lab(l3.y)], 1u);
                atomicAdd(&cnt[bucket_lab(l3.z)], 1u);
                atomicAdd(&cnt[bucket_lab(l3.w)], 1u);
            }
        }
        __syncthreads();
        unsigned* dst = pt1 + (size_t)rb * K;
        for (int c = tid; c < K; c += 1024) dst[c] = cnt[c];
    }
}

// ---------------------------------------------------------------------------
// P2a: merge per-block tables; unpack u64; store per-bucket AVG gain.
// ---------------------------------------------------------------------------
extern "C" __global__ void ndcg_reduce3(const unsigned long long* __restrict__ pt0,
                                        const unsigned* __restrict__ pt1,
                                        unsigned* __restrict__ base1, float* __restrict__ gs1,
                                        unsigned* __restrict__ base2, float* __restrict__ gs2,
                                        int nb) {
    int t = blockIdx.x * blockDim.x + threadIdx.x;
    if (t >= 2 * K) return;
    int table = t >> LOGK;
    int c = t & (K - 1);
    if (table == 0) {
        unsigned cs = 0u;
        unsigned long long hs = 0ull;
        const unsigned long long* p = pt0 + c;
        for (int b = 0; b < nb; ++b, p += K) {
            unsigned long long v = *p;
            cs += (unsigned)(v >> 47);
            hs += (v & GMASK);
        }
        base1[c] = cs;
        // sum(gain) = sum(gain+1) - count
        double gsum = (double)hs * (1.0 / (double)GSCALE) - (double)cs;
        gs1[c] = cs ? (float)(gsum / (double)cs) : 0.f;
    } else {
        unsigned cs = 0u;
        const unsigned* p = pt1 + c;
        for (int b = 0; b < nb; ++b, p += K) cs += *p;
        base2[c] = cs;
        // analytic mean gain at bucket center: labels in bucket c have
        // u = K-1-c, l in [u/K,(u+1)/K); center (u+0.5)/K
        float lc = ((float)(K - 1 - c) + 0.5f) * (1.0f / (float)K);
        gs2[c] = exp2f(fmaf(lc, RANGEF, LMINF)) - 1.0f;
    }
}

// ---------------------------------------------------------------------------
// P2b: in-place exclusive scan of counts -> bucket base ranks (+ total at
// base[K]); also zeroes the accumulator (runs before ndcg_walk).
// ---------------------------------------------------------------------------
extern "C" __global__ __launch_bounds__(1024)
void ndcg_scan3(unsigned* __restrict__ base1, unsigned* __restrict__ base2,
                double* __restrict__ acc) {
    unsigned* base = blockIdx.x ? base2 : base1;
    if (threadIdx.x == 0) acc[blockIdx.x] = 0.0;
    __shared__ unsigned sums[1024];
    const int t = threadIdx.x;
    const int chunk = K / 1024;           // 8
    unsigned v[8];
    unsigned s = 0u;
#pragma unroll
    for (int j = 0; j < chunk; ++j) { v[j] = base[t * chunk + j]; s += v[j]; }
    sums[t] = s;
    __syncthreads();
    for (int off = 1; off < 1024; off <<= 1) {
        unsigned add = (t >= off) ? sums[t - off] : 0u;
        __syncthreads();
        sums[t] += add;
        __syncthreads();
    }
    unsigned run = (t == 0) ? 0u : sums[t - 1];
#pragma unroll
    for (int j = 0; j < chunk; ++j) { unsigned x = v[j]; base[t * chunk + j] = run; run += x; }
    if (t == 1023) base[K] = run;         // = n
}

// ---------------------------------------------------------------------------
// P3: rank-major walk; binary-search bucket advance (empty-bucket deserts);
// per-rank cost = v_log_f32 + v_rcp_f32 + fma (avg precomputed per bucket).
// ---------------------------------------------------------------------------
__device__ __forceinline__ unsigned find_bucket(const unsigned* __restrict__ base,
                                                unsigned lo, unsigned hi, unsigned r) {
    while (hi - lo > 1u) {
        unsigned mid = (lo + hi) >> 1;
        if (base[mid] <= r) lo = mid; else hi = mid;
    }
    return lo;
}

__device__ __forceinline__ float walk_table(const unsigned* __restrict__ base,
                                            const float* __restrict__ avg,
                                            int r0, int r1) {
    unsigned b = find_bucket(base, 0u, K, (unsigned)r0);
    unsigned e = base[b + 1];
    float a = avg[b];
    float acc = 0.f;
    for (int r = r0; r < r1; ++r) {
        if ((unsigned)r >= e) {
            b = find_bucket(base, b + 1u, K, (unsigned)r);
            e = base[b + 1];
            a = avg[b];
        }
        acc += a * __builtin_amdgcn_rcpf(__log2f((float)(r + 2)));
    }
    return acc;
}

extern "C" __global__ void ndcg_walk(const unsigned* __restrict__ base1, const float* __restrict__ gs1,
                                     const unsigned* __restrict__ base2, const float* __restrict__ gs2,
                                     double* __restrict__ acc, int n, int C) {
    int tid = blockIdx.x * blockDim.x + threadIdx.x;
    long r0l = (long)tid * C;
    double ld = 0.0, lz = 0.0;
    if (r0l < (long)n) {
        int r0 = (int)r0l;
        int r1 = min(n, r0 + C);
        ld = (double)walk_table(base1, gs1, r0, r1);
        lz = (double)walk_table(base2, gs2, r0, r1);
    }
    for (int off = 32; off > 0; off >>= 1) {
        ld += __shfl_down(ld, off, 64);
        lz += __shfl_down(lz, off, 64);
    }
    __shared__ double sd[2][4];
    int wid = threadIdx.x >> 6, lane = threadIdx.x & 63;
    if (lane == 0) { sd[0][wid] = ld; sd[1][wid] = lz; }
    __syncthreads();
    if (threadIdx.x == 0) {
        atomicAdd(&acc[0], sd[0][0] + sd[0][1] + sd[0][2] + sd[0][3]);
        atomicAdd(&acc[1], sd[1][0] + sd[1][1] + sd[1][2] + sd[1][3]);
    }
}

extern "C" __global__ void ndcg_fin(const double* __restrict__ acc,
                                    float* __restrict__ out) {
    if (threadIdx.x == 0 && blockIdx.x == 0) out[0] = (float)(acc[0] / acc[1]);
}

extern "C" void kernel_launch(void* const* d_in, const int* in_sizes, int n_in,
                              void* d_out, int out_size, void* d_ws, size_t ws_size,
                              hipStream_t stream) {
    const float* sc = (const float*)d_in[0];
    const float* lb = (const float*)d_in[1];
    int n = in_sizes[0];
    int n4 = n / 4;

    // workspace layout
    char* p = (char*)d_ws;
    size_t off = 0;
    double*   acc   = (double*)(p + off);   off += 256;
    unsigned* base1 = (unsigned*)(p + off); off += ((size_t)(K + 1) * 4 + 255) & ~(size_t)255;
    unsigned* base2 = (unsigned*)(p + off); off += ((size_t)(K + 1) * 4 + 255) & ~(size_t)255;
    float*    gs1   = (float*)(p + off);    off += (size_t)K * 4;
    float*    gs2   = (float*)(p + off);    off += (size_t)K * 4;
    off = (off + 255) & ~(size_t)255;
    size_t fixed = off;

    // per-nb: role0 table K u64 + role1 table K u32 = 96 KB
    size_t per_nb = (size_t)K * 12;
    int nb = 256;
    if (fixed + (size_t)nb * per_nb > ws_size) {
        size_t avail = (ws_size > fixed) ? ws_size - fixed : 0;
        nb = (int)(avail / per_nb);
        if (nb < 1) nb = 1;
        if (nb > 256) nb = 256;
    }
    unsigned long long* pt0 = (unsigned long long*)(p + fixed);   // [nb][K] u64
    unsigned*           pt1 = (unsigned*)(p + fixed + (size_t)nb * K * 8); // [nb][K] u32

    ndcg_hist3<<<dim3(2 * nb), dim3(1024), 0, stream>>>(sc, lb, pt0, pt1, n4, nb);
    ndcg_reduce3<<<dim3((2 * K + 255) / 256), dim3(256), 0, stream>>>(pt0, pt1, base1, gs1, base2, gs2, nb);
    ndcg_scan3<<<dim3(2), dim3(1024), 0, stream>>>(base1, base2, acc);

    const int T = 2048 * 256;
    int C = (n + T - 1) / T;
    ndcg_walk<<<dim3(2048), dim3(256), 0, stream>>>(base1, gs1, base2, gs2, acc, n, C);
    ndcg_fin<<<dim3(1), dim3(64), 0, stream>>>(acc, (float*)d_out);
}

// Round 5
// 136.174 us; speedup vs baseline: 54.3343x; 1.3833x over previous
//
#include <hip/hip_runtime.h>
#include <hip/hip_bf16.h>

#define LOGK 13
#define K 8192
#define LMINF  -11.172813415527344f
#define RANGEF  25.154841423034668f   // LABEL_MAX - LABEL_MIN
#define GSCALE 65536.0f               // fixed-point scale for (gain+1) in packed u64
#define GMASK  ((1ULL << 47) - 1)
#define LN2D   0.6931471805599453
#define X0     4096                   // exact disc-prefix below this rank

// descending bucket of a float32 score via sortable-uint top bits
__device__ __forceinline__ unsigned bucket_out(float x) {
    unsigned u = __float_as_uint(x);
    unsigned key = u ^ ((u >> 31) ? 0xFFFFFFFFu : 0x80000000u);
    return (~key) >> (32 - LOGK);
}
// descending bucket of a label in [0,1)
__device__ __forceinline__ unsigned bucket_lab(float l) {
    unsigned u = (unsigned)(l * (float)K);
    if (u > (unsigned)(K - 1)) u = K - 1;
    return (unsigned)(K - 1) - u;
}

// ---------------------------------------------------------------------------
// P1: LDS-privatized histograms, 4-column batched loads for MLP.
// role 0: score histogram, packed u64 atomic: [63:47]=count, [46:0]=(gain+1)*2^16
// role 1: label histogram, u32 counts only (mean gain analytic per bucket)
// ---------------------------------------------------------------------------
extern "C" __global__ __launch_bounds__(1024)
void ndcg_hist3(const float* __restrict__ sc, const float* __restrict__ lb,
                unsigned long long* __restrict__ pt0, unsigned* __restrict__ pt1,
                int n4, int nb) {
    __shared__ unsigned long long pk[K];     // 64 KB; role 1 uses low 32 KB as u32
    const int bid  = blockIdx.x;
    const int role = (bid >= nb) ? 1 : 0;
    const int rb   = role ? bid - nb : bid;
    const int tid  = threadIdx.x;
    const float4* sc4 = (const float4*)sc;
    const float4* lb4 = (const float4*)lb;
    const int col = nb << 10;                // float4s per column

    if (role == 0) {
        for (int c = tid; c < K; c += 1024) pk[c] = 0ull;
        __syncthreads();
        for (int i = rb * 1024 + tid; i < n4; i += 4 * col) {
            int i1 = i + col, i2 = i + 2 * col, i3 = i + 3 * col;
            bool h1 = i1 < n4, h2 = i2 < n4, h3 = i3 < n4;
            float4 s0 = sc4[i],  l0 = lb4[i];
            float4 s1 = {}, l1 = {}, s2 = {}, l2 = {}, s3 = {}, l3 = {};
            if (h1) { s1 = sc4[i1]; l1 = lb4[i1]; }
            if (h2) { s2 = sc4[i2]; l2 = lb4[i2]; }
            if (h3) { s3 = sc4[i3]; l3 = lb4[i3]; }
            float ss[16] = {s0.x,s0.y,s0.z,s0.w, s1.x,s1.y,s1.z,s1.w,
                            s2.x,s2.y,s2.z,s2.w, s3.x,s3.y,s3.z,s3.w};
            float ll[16] = {l0.x,l0.y,l0.z,l0.w, l1.x,l1.y,l1.z,l1.w,
                            l2.x,l2.y,l2.z,l2.w, l3.x,l3.y,l3.z,l3.w};
            int lim = h3 ? 16 : (h2 ? 12 : (h1 ? 8 : 4));
            for (int j = 0; j < lim; ++j) {
                float h = exp2f(fmaf(ll[j], RANGEF, LMINF));   // gain+1 > 0
                unsigned gf = (unsigned)(h * GSCALE);
                atomicAdd(&pk[bucket_out(ss[j])], (1ULL << 47) | (unsigned long long)gf);
            }
        }
        __syncthreads();
        unsigned long long* dst = pt0 + (size_t)rb * K;
        for (int c = tid; c < K; c += 1024) dst[c] = pk[c];
    } else {
        unsigned* cnt = (unsigned*)pk;
        for (int c = tid; c < K; c += 1024) cnt[c] = 0u;
        __syncthreads();
        for (int i = rb * 1024 + tid; i < n4; i += 4 * col) {
            int i1 = i + col, i2 = i + 2 * col, i3 = i + 3 * col;
            bool h1 = i1 < n4, h2 = i2 < n4, h3 = i3 < n4;
            float4 l0 = lb4[i];
            float4 l1 = {}, l2 = {}, l3 = {};
            if (h1) l1 = lb4[i1];
            if (h2) l2 = lb4[i2];
            if (h3) l3 = lb4[i3];
            float ll[16] = {l0.x,l0.y,l0.z,l0.w, l1.x,l1.y,l1.z,l1.w,
                            l2.x,l2.y,l2.z,l2.w, l3.x,l3.y,l3.z,l3.w};
            int lim = h3 ? 16 : (h2 ? 12 : (h1 ? 8 : 4));
            for (int j = 0; j < lim; ++j)
                atomicAdd(&cnt[bucket_lab(ll[j])], 1u);
        }
        __syncthreads();
        unsigned* dst = pt1 + (size_t)rb * K;
        for (int c = tid; c < K; c += 1024) dst[c] = cnt[c];
    }
}

// ---------------------------------------------------------------------------
// P2a: merge per-block tables; unpack u64; store per-bucket AVG gain.
// ---------------------------------------------------------------------------
extern "C" __global__ void ndcg_reduce3(const unsigned long long* __restrict__ pt0,
                                        const unsigned* __restrict__ pt1,
                                        unsigned* __restrict__ base1, float* __restrict__ gs1,
                                        unsigned* __restrict__ base2, float* __restrict__ gs2,
                                        int nb) {
    int t = blockIdx.x * blockDim.x + threadIdx.x;
    if (t >= 2 * K) return;
    int table = t >> LOGK;
    int c = t & (K - 1);
    if (table == 0) {
        unsigned cs = 0u;
        unsigned long long hs = 0ull;
        const unsigned long long* p = pt0 + c;
        for (int b = 0; b < nb; ++b, p += K) {
            unsigned long long v = *p;
            cs += (unsigned)(v >> 47);
            hs += (v & GMASK);
        }
        base1[c] = cs;
        double gsum = (double)hs * (1.0 / (double)GSCALE) - (double)cs;
        gs1[c] = cs ? (float)(gsum / (double)cs) : 0.f;
    } else {
        unsigned cs = 0u;
        const unsigned* p = pt1 + c;
        for (int b = 0; b < nb; ++b, p += K) cs += *p;
        base2[c] = cs;
        float lc = ((float)(K - 1 - c) + 0.5f) * (1.0f / (float)K);
        gs2[c] = exp2f(fmaf(lc, RANGEF, LMINF)) - 1.0f;
    }
}

// ---------------------------------------------------------------------------
// P2b: blocks 0/1: in-place exclusive scan of counts -> bucket base ranks
// (+ total at base[K]); zero acc. Block 2: exact f64 disc-prefix Dex[0..X0].
// ---------------------------------------------------------------------------
extern "C" __global__ __launch_bounds__(1024)
void ndcg_scan3(unsigned* __restrict__ base1, unsigned* __restrict__ base2,
                double* __restrict__ Dex, double* __restrict__ acc) {
    const int t = threadIdx.x;
    if (blockIdx.x < 2) {
        unsigned* base = blockIdx.x ? base2 : base1;
        if (t == 0) acc[blockIdx.x] = 0.0;
        __shared__ unsigned sums[1024];
        const int chunk = K / 1024;           // 8
        unsigned v[8];
        unsigned s = 0u;
#pragma unroll
        for (int j = 0; j < chunk; ++j) { v[j] = base[t * chunk + j]; s += v[j]; }
        sums[t] = s;
        __syncthreads();
        for (int off = 1; off < 1024; off <<= 1) {
            unsigned add = (t >= off) ? sums[t - off] : 0u;
            __syncthreads();
            sums[t] += add;
            __syncthreads();
        }
        unsigned run = (t == 0) ? 0u : sums[t - 1];
#pragma unroll
        for (int j = 0; j < chunk; ++j) { unsigned x = v[j]; base[t * chunk + j] = run; run += x; }
        if (t == 1023) base[K] = run;         // = n
    } else {
        // exact disc prefix: Dex[x] = sum_{r<x} ln2/ln(r+2), x in [0, X0]
        __shared__ double sd[1024];
        double d[4];
        double part = 0.0;
#pragma unroll
        for (int j = 0; j < 4; ++j) {
            int r = t * 4 + j;
            d[j] = LN2D / log((double)(r + 2));
            part += d[j];
        }
        sd[t] = part;
        __syncthreads();
        for (int off = 1; off < 1024; off <<= 1) {
            double add = (t >= off) ? sd[t - off] : 0.0;
            __syncthreads();
            sd[t] += add;
            __syncthreads();
        }
        double run = (t == 0) ? 0.0 : sd[t - 1];
        if (t == 0) Dex[0] = 0.0;
#pragma unroll
        for (int j = 0; j < 4; ++j) { run += d[j]; Dex[t * 4 + j + 1] = run; }
    }
}

// ---------------------------------------------------------------------------
// P3: analytic bucket-sum kernel (replaces per-rank walk).
//  S(x) = sum_{r<x} disc(r); exact table for x<=X0, Euler-Maclaurin + li(x)
//  beyond. li series is all-positive (no cancellation), 64 terms, f64.
// ---------------------------------------------------------------------------
__device__ double li_x(double x) {
    double lx = log(x);
    double term = 1.0, sum = 0.0;
    for (int k = 1; k <= 64; ++k) {
        term *= lx / (double)k;
        sum += term / (double)k;
    }
    return 0.5772156649015329 + log(lx) + sum;
}

__device__ double S_of(const double* __restrict__ Dex, unsigned x) {
    if (x <= (unsigned)X0) return Dex[x];
    // ranks X0..x-1  ->  u = r+2 in [X0+2, x+1], f(u)=1/ln u
    double A = (double)(X0 + 2), B = (double)x + 1.0;
    double lA = log(A), lB = log(B);
    double integral = li_x(B) - li_x(A);
    double edge = 0.5 * (1.0 / lA + 1.0 / lB);
    double der  = (1.0 / (A * lA * lA) - 1.0 / (B * lB * lB)) * (1.0 / 12.0);
    return Dex[X0] + LN2D * (integral + edge + der);
}

extern "C" __global__ void ndcg_bucket(const unsigned* __restrict__ base1, const float* __restrict__ gs1,
                                       const unsigned* __restrict__ base2, const float* __restrict__ gs2,
                                       const double* __restrict__ Dex, double* __restrict__ acc) {
    int t = blockIdx.x * blockDim.x + threadIdx.x;
    int table = t >> LOGK;
    int c = t & (K - 1);
    const unsigned* base = table ? base2 : base1;
    const float*    avg  = table ? gs2   : gs1;
    double ld = 0.0, lz = 0.0;
    unsigned a = base[c], e = base[c + 1];
    if (e > a) {
        double s = S_of(Dex, e) - S_of(Dex, a);
        double contrib = (double)avg[c] * s;
        if (table == 0) ld = contrib; else lz = contrib;
    }
    for (int off = 32; off > 0; off >>= 1) {
        ld += __shfl_down(ld, off, 64);
        lz += __shfl_down(lz, off, 64);
    }
    __shared__ double sd[2][4];
    int wid = threadIdx.x >> 6, lane = threadIdx.x & 63;
    if (lane == 0) { sd[0][wid] = ld; sd[1][wid] = lz; }
    __syncthreads();
    if (threadIdx.x == 0) {
        double a0 = sd[0][0] + sd[0][1] + sd[0][2] + sd[0][3];
        double b0 = sd[1][0] + sd[1][1] + sd[1][2] + sd[1][3];
        if (a0 != 0.0) atomicAdd(&acc[0], a0);
        if (b0 != 0.0) atomicAdd(&acc[1], b0);
    }
}

extern "C" __global__ void ndcg_fin(const double* __restrict__ acc,
                                    float* __restrict__ out) {
    if (threadIdx.x == 0 && blockIdx.x == 0) out[0] = (float)(acc[0] / acc[1]);
}

extern "C" void kernel_launch(void* const* d_in, const int* in_sizes, int n_in,
                              void* d_out, int out_size, void* d_ws, size_t ws_size,
                              hipStream_t stream) {
    const float* sc = (const float*)d_in[0];
    const float* lb = (const float*)d_in[1];
    int n = in_sizes[0];
    int n4 = n / 4;

    // workspace layout
    char* p = (char*)d_ws;
    size_t off = 0;
    double*   acc   = (double*)(p + off);   off += 256;
    unsigned* base1 = (unsigned*)(p + off); off += ((size_t)(K + 1) * 4 + 255) & ~(size_t)255;
    unsigned* base2 = (unsigned*)(p + off); off += ((size_t)(K + 1) * 4 + 255) & ~(size_t)255;
    float*    gs1   = (float*)(p + off);    off += (size_t)K * 4;
    float*    gs2   = (float*)(p + off);    off += (size_t)K * 4;
    off = (off + 255) & ~(size_t)255;
    double*   Dex   = (double*)(p + off);   off += ((size_t)(X0 + 1) * 8 + 255) & ~(size_t)255;
    size_t fixed = off;

    // per-nb: role0 table K u64 + role1 table K u32 = 96 KB
    size_t per_nb = (size_t)K * 12;
    int nb = 256;
    if (fixed + (size_t)nb * per_nb > ws_size) {
        size_t avail = (ws_size > fixed) ? ws_size - fixed : 0;
        nb = (int)(avail / per_nb);
        if (nb < 1) nb = 1;
        if (nb > 256) nb = 256;
    }
    unsigned long long* pt0 = (unsigned long long*)(p + fixed);
    unsigned*           pt1 = (unsigned*)(p + fixed + (size_t)nb * K * 8);

    ndcg_hist3<<<dim3(2 * nb), dim3(1024), 0, stream>>>(sc, lb, pt0, pt1, n4, nb);
    ndcg_reduce3<<<dim3((2 * K + 255) / 256), dim3(256), 0, stream>>>(pt0, pt1, base1, gs1, base2, gs2, nb);
    ndcg_scan3<<<dim3(3), dim3(1024), 0, stream>>>(base1, base2, Dex, acc);
    ndcg_bucket<<<dim3(2 * K / 256), dim3(256), 0, stream>>>(base1, gs1, base2, gs2, Dex, acc);
    ndcg_fin<<<dim3(1), dim3(64), 0, stream>>>(acc, (float*)d_out);
}

// Round 6
// 68.819 us; speedup vs baseline: 107.5122x; 1.9787x over previous
//
#include <hip/hip_runtime.h>
#include <hip/hip_bf16.h>

#define LOGK 13
#define K 8192
#define LMINF  -11.172813415527344f
#define RANGEF  25.154841423034668f   // LABEL_MAX - LABEL_MIN
#define GSCALE 65536.0
#define GSCALEF 65536.0f
#define GMASK  ((1ULL << 47) - 1)
#define LN2D   0.6931471805599453
#define X0     4096                   // exact disc-prefix below this rank

// descending bucket of a float32 score via sortable-uint top bits
__device__ __forceinline__ unsigned bucket_out(float x) {
    unsigned u = __float_as_uint(x);
    unsigned key = u ^ ((u >> 31) ? 0xFFFFFFFFu : 0x80000000u);
    return (~key) >> (32 - LOGK);
}
// descending bucket of a label in [0,1)
__device__ __forceinline__ unsigned bucket_lab(float l) {
    unsigned u = (unsigned)(l * (float)K);
    if (u > (unsigned)(K - 1)) u = K - 1;
    return (unsigned)(K - 1) - u;
}

// ---------------------------------------------------------------------------
// P1: ONE pass builds BOTH histograms (lb read once, not twice).
//  pk[K]  u64 packed: [63:47]=count, [46:0]=(gain+1)*2^16 (per-block count
//         <= n/nb = 65536 < 2^17; per-block hs <= 6.9e13 < 2^47 — safe).
//  cnt2[K] u32 label counts (mean label-gain is analytic per bucket).
// 96 KB LDS -> 1 block/CU; 4-column batched loads keep 8 loads in flight.
// ---------------------------------------------------------------------------
extern "C" __global__ __launch_bounds__(1024)
void ndcg_hist4(const float* __restrict__ sc, const float* __restrict__ lb,
                unsigned long long* __restrict__ pt0, unsigned* __restrict__ pt1,
                int n4, int nb) {
    __shared__ unsigned long long pk[K];     // 64 KB
    __shared__ unsigned cnt2[K];             // 32 KB
    const int rb  = blockIdx.x;
    const int tid = threadIdx.x;
    for (int c = tid; c < K; c += 1024) { pk[c] = 0ull; cnt2[c] = 0u; }
    __syncthreads();
    const float4* sc4 = (const float4*)sc;
    const float4* lb4 = (const float4*)lb;
    const int col = nb << 10;                // float4s per column
    for (int i = rb * 1024 + tid; i < n4; i += 4 * col) {
        int i1 = i + col, i2 = i + 2 * col, i3 = i + 3 * col;
        bool h1 = i1 < n4, h2 = i2 < n4, h3 = i3 < n4;
        float4 s0 = sc4[i],  l0 = lb4[i];
        float4 s1 = {}, l1 = {}, s2 = {}, l2 = {}, s3 = {}, l3 = {};
        if (h1) { s1 = sc4[i1]; l1 = lb4[i1]; }
        if (h2) { s2 = sc4[i2]; l2 = lb4[i2]; }
        if (h3) { s3 = sc4[i3]; l3 = lb4[i3]; }
        float ss[16] = {s0.x,s0.y,s0.z,s0.w, s1.x,s1.y,s1.z,s1.w,
                        s2.x,s2.y,s2.z,s2.w, s3.x,s3.y,s3.z,s3.w};
        float ll[16] = {l0.x,l0.y,l0.z,l0.w, l1.x,l1.y,l1.z,l1.w,
                        l2.x,l2.y,l2.z,l2.w, l3.x,l3.y,l3.z,l3.w};
        int lim = h3 ? 16 : (h2 ? 12 : (h1 ? 8 : 4));
        for (int j = 0; j < lim; ++j) {
            float h = exp2f(fmaf(ll[j], RANGEF, LMINF));   // gain+1 > 0
            unsigned gf = (unsigned)(h * GSCALEF);
            atomicAdd(&pk[bucket_out(ss[j])], (1ULL << 47) | (unsigned long long)gf);
            atomicAdd(&cnt2[bucket_lab(ll[j])], 1u);
        }
    }
    __syncthreads();
    unsigned long long* d0 = pt0 + (size_t)rb * K;
    unsigned*           d1 = pt1 + (size_t)rb * K;
    for (int c = tid; c < K; c += 1024) { d0[c] = pk[c]; d1[c] = cnt2[c]; }
}

// ---------------------------------------------------------------------------
// P2a: 32x-parallel merge. grid (K/256, ceil(nb/8), 2). Each thread sums 8
// rows (8 independent loads in flight) and does one NON-RETURNING global
// atomicAdd per accumulator (32 hits/address — negligible contention).
// gc/gh accumulators are pre-zeroed by a memsetAsync each call.
// ---------------------------------------------------------------------------
extern "C" __global__ void ndcg_reduce4(const unsigned long long* __restrict__ pt0,
                                        const unsigned* __restrict__ pt1,
                                        unsigned* __restrict__ gc1,
                                        unsigned long long* __restrict__ gh1,
                                        unsigned* __restrict__ gc2, int nb) {
    const int c  = blockIdx.x * 256 + threadIdx.x;
    const int r0 = blockIdx.y * 8;
    const int r1 = min(r0 + 8, nb);
    if (blockIdx.z == 0) {
        unsigned cs = 0u; unsigned long long hs = 0ull;
        const unsigned long long* p = pt0 + (size_t)r0 * K + c;
        if (r1 - r0 == 8) {
            unsigned long long v0=p[0],v1=p[K],v2=p[2*K],v3=p[3*K],
                               v4=p[4*(size_t)K],v5=p[5*(size_t)K],v6=p[6*(size_t)K],v7=p[7*(size_t)K];
            cs = (unsigned)((v0>>47)+(v1>>47)+(v2>>47)+(v3>>47)+(v4>>47)+(v5>>47)+(v6>>47)+(v7>>47));
            hs = (v0&GMASK)+(v1&GMASK)+(v2&GMASK)+(v3&GMASK)+(v4&GMASK)+(v5&GMASK)+(v6&GMASK)+(v7&GMASK);
        } else {
            for (int r = r0; r < r1; ++r, p += K) {
                unsigned long long v = *p;
                cs += (unsigned)(v >> 47);
                hs += (v & GMASK);
            }
        }
        atomicAdd(&gc1[c], cs);
        atomicAdd(&gh1[c], hs);
    } else {
        unsigned cs = 0u;
        const unsigned* p = pt1 + (size_t)r0 * K + c;
        if (r1 - r0 == 8) {
            cs = p[0]+p[K]+p[2*K]+p[3*K]+p[4*(size_t)K]+p[5*(size_t)K]+p[6*(size_t)K]+p[7*(size_t)K];
        } else {
            for (int r = r0; r < r1; ++r, p += K) cs += *p;
        }
        atomicAdd(&gc2[c], cs);
    }
}

// ---------------------------------------------------------------------------
// P2b: blocks 0/1: exclusive scan gcX -> baseX (+ total at base[K]); zero acc.
// Block 2: exact f64 disc-prefix Dex[0..X0].
// ---------------------------------------------------------------------------
extern "C" __global__ __launch_bounds__(1024)
void ndcg_scan4(const unsigned* __restrict__ gc1, const unsigned* __restrict__ gc2,
                unsigned* __restrict__ base1, unsigned* __restrict__ base2,
                double* __restrict__ Dex, double* __restrict__ acc) {
    const int t = threadIdx.x;
    if (blockIdx.x < 2) {
        const unsigned* in  = blockIdx.x ? gc2 : gc1;
        unsigned*       out = blockIdx.x ? base2 : base1;
        if (t == 0) acc[blockIdx.x] = 0.0;
        __shared__ unsigned sums[1024];
        const int chunk = K / 1024;           // 8
        unsigned v[8];
        unsigned s = 0u;
#pragma unroll
        for (int j = 0; j < chunk; ++j) { v[j] = in[t * chunk + j]; s += v[j]; }
        sums[t] = s;
        __syncthreads();
        for (int off = 1; off < 1024; off <<= 1) {
            unsigned add = (t >= off) ? sums[t - off] : 0u;
            __syncthreads();
            sums[t] += add;
            __syncthreads();
        }
        unsigned run = (t == 0) ? 0u : sums[t - 1];
#pragma unroll
        for (int j = 0; j < chunk; ++j) { unsigned x = v[j]; out[t * chunk + j] = run; run += x; }
        if (t == 1023) out[K] = run;          // = n
    } else {
        __shared__ double sd[1024];
        double d[4];
        double part = 0.0;
#pragma unroll
        for (int j = 0; j < 4; ++j) {
            int r = t * 4 + j;
            d[j] = LN2D / log((double)(r + 2));
            part += d[j];
        }
        sd[t] = part;
        __syncthreads();
        for (int off = 1; off < 1024; off <<= 1) {
            double add = (t >= off) ? sd[t - off] : 0.0;
            __syncthreads();
            sd[t] += add;
            __syncthreads();
        }
        double run = (t == 0) ? 0.0 : sd[t - 1];
        if (t == 0) Dex[0] = 0.0;
#pragma unroll
        for (int j = 0; j < 4; ++j) { run += d[j]; Dex[t * 4 + j + 1] = run; }
    }
}

// ---------------------------------------------------------------------------
// P3: analytic per-bucket contribution. S(x)=sum_{r<x} 1/log2(r+2): exact
// table below X0, Euler-Maclaurin + li(x) beyond (all-positive series, f64).
// ---------------------------------------------------------------------------
__device__ double li_x(double x) {
    double lx = log(x);
    double term = 1.0, sum = 0.0;
    for (int k = 1; k <= 64; ++k) {
        term *= lx / (double)k;
        sum += term / (double)k;
    }
    return 0.5772156649015329 + log(lx) + sum;
}

__device__ double S_of(const double* __restrict__ Dex, unsigned x) {
    if (x <= (unsigned)X0) return Dex[x];
    double A = (double)(X0 + 2), B = (double)x + 1.0;
    double lA = log(A), lB = log(B);
    double integral = li_x(B) - li_x(A);
    double edge = 0.5 * (1.0 / lA + 1.0 / lB);
    double der  = (1.0 / (A * lA * lA) - 1.0 / (B * lB * lB)) * (1.0 / 12.0);
    return Dex[X0] + LN2D * (integral + edge + der);
}

extern "C" __global__ void ndcg_bucket(const unsigned* __restrict__ base1,
                                       const unsigned long long* __restrict__ gh1,
                                       const unsigned* __restrict__ base2,
                                       const double* __restrict__ Dex,
                                       double* __restrict__ acc) {
    int t = blockIdx.x * blockDim.x + threadIdx.x;
    int table = t >> LOGK;
    int c = t & (K - 1);
    double ld = 0.0, lz = 0.0;
    if (table == 0) {
        unsigned a = base1[c], e = base1[c + 1];
        if (e > a) {
            unsigned cnt = e - a;
            double gsum = (double)gh1[c] * (1.0 / GSCALE) - (double)cnt;  // sum(gain)
            ld = (gsum / (double)cnt) * (S_of(Dex, e) - S_of(Dex, a));
        }
    } else {
        unsigned a = base2[c], e = base2[c + 1];
        if (e > a) {
            float lc = ((float)(K - 1 - c) + 0.5f) * (1.0f / (float)K);
            double avg = (double)(exp2f(fmaf(lc, RANGEF, LMINF)) - 1.0f);
            lz = avg * (S_of(Dex, e) - S_of(Dex, a));
        }
    }
    for (int off = 32; off > 0; off >>= 1) {
        ld += __shfl_down(ld, off, 64);
        lz += __shfl_down(lz, off, 64);
    }
    __shared__ double sd[2][4];
    int wid = threadIdx.x >> 6, lane = threadIdx.x & 63;
    if (lane == 0) { sd[0][wid] = ld; sd[1][wid] = lz; }
    __syncthreads();
    if (threadIdx.x == 0) {
        double a0 = sd[0][0] + sd[0][1] + sd[0][2] + sd[0][3];
        double b0 = sd[1][0] + sd[1][1] + sd[1][2] + sd[1][3];
        if (a0 != 0.0) atomicAdd(&acc[0], a0);
        if (b0 != 0.0) atomicAdd(&acc[1], b0);
    }
}

extern "C" __global__ void ndcg_fin(const double* __restrict__ acc,
                                    float* __restrict__ out) {
    if (threadIdx.x == 0 && blockIdx.x == 0) out[0] = (float)(acc[0] / acc[1]);
}

extern "C" void kernel_launch(void* const* d_in, const int* in_sizes, int n_in,
                              void* d_out, int out_size, void* d_ws, size_t ws_size,
                              hipStream_t stream) {
    const float* sc = (const float*)d_in[0];
    const float* lb = (const float*)d_in[1];
    int n = in_sizes[0];
    int n4 = n / 4;

    // workspace layout
    char* p = (char*)d_ws;
    size_t off = 0;
    double*             acc   = (double*)(p + off);             off += 256;
    unsigned long long* gh1   = (unsigned long long*)(p + off); off += (size_t)K * 8;
    unsigned*           gc1   = (unsigned*)(p + off);           off += (size_t)K * 4;
    unsigned*           gc2   = (unsigned*)(p + off);           off += (size_t)K * 4;  // gh1..gc2 = K*16 contiguous
    unsigned*           base1 = (unsigned*)(p + off);           off += ((size_t)(K + 1) * 4 + 255) & ~(size_t)255;
    unsigned*           base2 = (unsigned*)(p + off);           off += ((size_t)(K + 1) * 4 + 255) & ~(size_t)255;
    double*             Dex   = (double*)(p + off);             off += ((size_t)(X0 + 1) * 8 + 255) & ~(size_t)255;
    size_t fixed = off;

    // per-nb: K u64 (packed score table) + K u32 (label counts) = 96 KB
    size_t per_nb = (size_t)K * 12;
    int nb = 256;
    if (fixed + (size_t)nb * per_nb > ws_size) {
        size_t avail = (ws_size > fixed) ? ws_size - fixed : 0;
        nb = (int)(avail / per_nb);
        if (nb < 1) nb = 1;
        if (nb > 256) nb = 256;
    }
    // note: packed count field (17 bits) is safe for nb >= 129 with any data;
    // below that it relies on no single bucket holding a whole block's items.
    unsigned long long* pt0 = (unsigned long long*)(p + fixed);
    unsigned*           pt1 = (unsigned*)(p + fixed + (size_t)nb * K * 8);

    hipMemsetAsync(gh1, 0, (size_t)K * 16, stream);   // gh1 + gc1 + gc2

    ndcg_hist4<<<dim3(nb), dim3(1024), 0, stream>>>(sc, lb, pt0, pt1, n4, nb);
    int G = (nb + 7) / 8;
    ndcg_reduce4<<<dim3(K / 256, G, 2), dim3(256), 0, stream>>>(pt0, pt1, gc1, gh1, gc2, nb);
    ndcg_scan4<<<dim3(3), dim3(1024), 0, stream>>>(gc1, gc2, base1, base2, Dex, acc);
    ndcg_bucket<<<dim3(2 * K / 256), dim3(256), 0, stream>>>(base1, gh1, base2, Dex, acc);
    ndcg_fin<<<dim3(1), dim3(64), 0, stream>>>(acc, (float*)d_out);
}

// Round 7
// 68.368 us; speedup vs baseline: 108.2212x; 1.0066x over previous
//
#include <hip/hip_runtime.h>
#include <hip/hip_bf16.h>

#define LOGK 12
#define K 4096
#define LMINF  -11.172813415527344f
#define RANGEF  25.154841423034668f   // LABEL_MAX - LABEL_MIN
#define GSCALE 65536.0
#define GSCALEF 65536.0f
#define GMASK  ((1ULL << 47) - 1)
#define LN2D   0.6931471805599453
#define X0     4096                   // exact disc-prefix below this rank

// descending bucket of a float32 score via sortable-uint top bits
__device__ __forceinline__ unsigned bucket_out(float x) {
    unsigned u = __float_as_uint(x);
    unsigned key = u ^ ((u >> 31) ? 0xFFFFFFFFu : 0x80000000u);
    return (~key) >> (32 - LOGK);
}
// descending bucket of a label in [0,1)
__device__ __forceinline__ unsigned bucket_lab(float l) {
    unsigned u = (unsigned)(l * (float)K);
    if (u > (unsigned)(K - 1)) u = K - 1;
    return (unsigned)(K - 1) - u;
}

// ---------------------------------------------------------------------------
// P1: ONE pass builds BOTH histograms; LDS 48 KB -> 2 blocks/CU (100% occ).
//  pk[K]  u64 packed: [63:47]=count (per-block <= 2^16), [46:0]=(gain+1)*2^16
//  cnt2[K] u32 label counts (label-bucket mean gain is analytic).
// Block merges LDS tables straight into global accumulators (non-returning
// atomics, 256 hits/address) — no per-block tables, no reduce kernel.
// All item processing uses constant indices (no runtime-indexed arrays).
// ---------------------------------------------------------------------------
#define ITEM(S, L)                                                             \
    {                                                                          \
        float h_ = exp2f(fmaf((L), RANGEF, LMINF)); /* gain+1 > 0 */           \
        unsigned gf_ = (unsigned)(h_ * GSCALEF);                               \
        atomicAdd(&pk[bucket_out(S)], (1ULL << 47) | (unsigned long long)gf_); \
        atomicAdd(&cnt2[bucket_lab(L)], 1u);                                   \
    }

extern "C" __global__ __launch_bounds__(1024, 8)
void ndcg_hist5(const float* __restrict__ sc, const float* __restrict__ lb,
                unsigned* __restrict__ gc1, unsigned long long* __restrict__ gh1,
                unsigned* __restrict__ gc2, int n4, int nb) {
    __shared__ unsigned long long pk[K];     // 32 KB
    __shared__ unsigned cnt2[K];             // 16 KB
    const int rb  = blockIdx.x;
    const int tid = threadIdx.x;
    for (int c = tid; c < K; c += 1024) { pk[c] = 0ull; cnt2[c] = 0u; }
    __syncthreads();
    const float4* sc4 = (const float4*)sc;
    const float4* lb4 = (const float4*)lb;
    const int col = nb << 10;                // float4s per column
    for (int i = rb * 1024 + tid; i < n4; i += 4 * col) {
        int i1 = i + col, i2 = i + 2 * col, i3 = i + 3 * col;
        bool h1 = i1 < n4, h2 = i2 < n4, h3 = i3 < n4;
        float4 s0 = sc4[i],  l0 = lb4[i];
        float4 s1 = {}, l1 = {}, s2 = {}, l2 = {}, s3 = {}, l3 = {};
        if (h1) { s1 = sc4[i1]; l1 = lb4[i1]; }
        if (h2) { s2 = sc4[i2]; l2 = lb4[i2]; }
        if (h3) { s3 = sc4[i3]; l3 = lb4[i3]; }
        ITEM(s0.x, l0.x) ITEM(s0.y, l0.y) ITEM(s0.z, l0.z) ITEM(s0.w, l0.w)
        if (h1) { ITEM(s1.x, l1.x) ITEM(s1.y, l1.y) ITEM(s1.z, l1.z) ITEM(s1.w, l1.w) }
        if (h2) { ITEM(s2.x, l2.x) ITEM(s2.y, l2.y) ITEM(s2.z, l2.z) ITEM(s2.w, l2.w) }
        if (h3) { ITEM(s3.x, l3.x) ITEM(s3.y, l3.y) ITEM(s3.z, l3.z) ITEM(s3.w, l3.w) }
    }
    __syncthreads();
    // merge to global (counts u32, gain-sums u64 — split so counts can't
    // overflow the 17-bit packed field globally)
    for (int c = tid; c < K; c += 1024) {
        unsigned long long v = pk[c];
        if (v) {
            atomicAdd(&gc1[c], (unsigned)(v >> 47));
            atomicAdd(&gh1[c], v & GMASK);
        }
        unsigned c2 = cnt2[c];
        if (c2) atomicAdd(&gc2[c], c2);
    }
}

// ---------------------------------------------------------------------------
// P2: blocks 0/1: exclusive scan gcX -> baseX (+ total at base[K]); zero acc.
// Block 2: exact f64 disc-prefix Dex[0..X0].
// ---------------------------------------------------------------------------
extern "C" __global__ __launch_bounds__(1024)
void ndcg_scan5(const unsigned* __restrict__ gc1, const unsigned* __restrict__ gc2,
                unsigned* __restrict__ base1, unsigned* __restrict__ base2,
                double* __restrict__ Dex, double* __restrict__ acc) {
    const int t = threadIdx.x;
    if (blockIdx.x < 2) {
        const unsigned* in  = blockIdx.x ? gc2 : gc1;
        unsigned*       out = blockIdx.x ? base2 : base1;
        if (t == 0) acc[blockIdx.x] = 0.0;
        __shared__ unsigned sums[1024];
        const int chunk = K / 1024;           // 4
        unsigned v[4];
        unsigned s = 0u;
#pragma unroll
        for (int j = 0; j < chunk; ++j) { v[j] = in[t * chunk + j]; s += v[j]; }
        sums[t] = s;
        __syncthreads();
        for (int off = 1; off < 1024; off <<= 1) {
            unsigned add = (t >= off) ? sums[t - off] : 0u;
            __syncthreads();
            sums[t] += add;
            __syncthreads();
        }
        unsigned run = (t == 0) ? 0u : sums[t - 1];
#pragma unroll
        for (int j = 0; j < chunk; ++j) { unsigned x = v[j]; out[t * chunk + j] = run; run += x; }
        if (t == 1023) out[K] = run;          // = n
    } else {
        __shared__ double sd[1024];
        double d[4];
        double part = 0.0;
#pragma unroll
        for (int j = 0; j < 4; ++j) {
            int r = t * 4 + j;
            d[j] = LN2D / log((double)(r + 2));
            part += d[j];
        }
        sd[t] = part;
        __syncthreads();
        for (int off = 1; off < 1024; off <<= 1) {
            double add = (t >= off) ? sd[t - off] : 0.0;
            __syncthreads();
            sd[t] += add;
            __syncthreads();
        }
        double run = (t == 0) ? 0.0 : sd[t - 1];
        if (t == 0) Dex[0] = 0.0;
#pragma unroll
        for (int j = 0; j < 4; ++j) { run += d[j]; Dex[t * 4 + j + 1] = run; }
    }
}

// ---------------------------------------------------------------------------
// P3: analytic per-bucket contribution. S(x)=sum_{r<x} 1/log2(r+2): exact
// table below X0, Euler-Maclaurin + li(x) beyond (all-positive series, f64).
// ---------------------------------------------------------------------------
__device__ double li_x(double x) {
    double lx = log(x);
    double term = 1.0, sum = 0.0;
    for (int k = 1; k <= 64; ++k) {
        term *= lx / (double)k;
        sum += term / (double)k;
    }
    return 0.5772156649015329 + log(lx) + sum;
}

__device__ double S_of(const double* __restrict__ Dex, unsigned x) {
    if (x <= (unsigned)X0) return Dex[x];
    double A = (double)(X0 + 2), B = (double)x + 1.0;
    double lA = log(A), lB = log(B);
    double integral = li_x(B) - li_x(A);
    double edge = 0.5 * (1.0 / lA + 1.0 / lB);
    double der  = (1.0 / (A * lA * lA) - 1.0 / (B * lB * lB)) * (1.0 / 12.0);
    return Dex[X0] + LN2D * (integral + edge + der);
}

extern "C" __global__ void ndcg_bucket(const unsigned* __restrict__ base1,
                                       const unsigned long long* __restrict__ gh1,
                                       const unsigned* __restrict__ base2,
                                       const double* __restrict__ Dex,
                                       double* __restrict__ acc) {
    int t = blockIdx.x * blockDim.x + threadIdx.x;
    int table = t >> LOGK;
    int c = t & (K - 1);
    double ld = 0.0, lz = 0.0;
    if (table == 0) {
        unsigned a = base1[c], e = base1[c + 1];
        if (e > a) {
            unsigned cnt = e - a;
            double gsum = (double)gh1[c] * (1.0 / GSCALE) - (double)cnt; // sum(gain)
            ld = (gsum / (double)cnt) * (S_of(Dex, e) - S_of(Dex, a));
        }
    } else {
        unsigned a = base2[c], e = base2[c + 1];
        if (e > a) {
            float lc = ((float)(K - 1 - c) + 0.5f) * (1.0f / (float)K);
            double avg = (double)(exp2f(fmaf(lc, RANGEF, LMINF)) - 1.0f);
            lz = avg * (S_of(Dex, e) - S_of(Dex, a));
        }
    }
    for (int off = 32; off > 0; off >>= 1) {
        ld += __shfl_down(ld, off, 64);
        lz += __shfl_down(lz, off, 64);
    }
    __shared__ double sd[2][4];
    int wid = threadIdx.x >> 6, lane = threadIdx.x & 63;
    if (lane == 0) { sd[0][wid] = ld; sd[1][wid] = lz; }
    __syncthreads();
    if (threadIdx.x == 0) {
        double a0 = sd[0][0] + sd[0][1] + sd[0][2] + sd[0][3];
        double b0 = sd[1][0] + sd[1][1] + sd[1][2] + sd[1][3];
        if (a0 != 0.0) atomicAdd(&acc[0], a0);
        if (b0 != 0.0) atomicAdd(&acc[1], b0);
    }
}

extern "C" __global__ void ndcg_fin(const double* __restrict__ acc,
                                    float* __restrict__ out) {
    if (threadIdx.x == 0 && blockIdx.x == 0) out[0] = (float)(acc[0] / acc[1]);
}

extern "C" void kernel_launch(void* const* d_in, const int* in_sizes, int n_in,
                              void* d_out, int out_size, void* d_ws, size_t ws_size,
                              hipStream_t stream) {
    const float* sc = (const float*)d_in[0];
    const float* lb = (const float*)d_in[1];
    int n = in_sizes[0];
    int n4 = n / 4;

    // workspace layout (gh1,gc1,gc2 contiguous for one memset)
    char* p = (char*)d_ws;
    size_t off = 0;
    double*             acc   = (double*)(p + off);             off += 256;
    unsigned long long* gh1   = (unsigned long long*)(p + off); off += (size_t)K * 8;
    unsigned*           gc1   = (unsigned*)(p + off);           off += (size_t)K * 4;
    unsigned*           gc2   = (unsigned*)(p + off);           off += (size_t)K * 4;
    unsigned*           base1 = (unsigned*)(p + off);           off += ((size_t)(K + 1) * 4 + 255) & ~(size_t)255;
    unsigned*           base2 = (unsigned*)(p + off);           off += ((size_t)(K + 1) * 4 + 255) & ~(size_t)255;
    double*             Dex   = (double*)(p + off);             off += ((size_t)(X0 + 1) * 8 + 255) & ~(size_t)255;

    const int nb = 256;   // tables are global-atomic-merged; no per-nb storage

    hipMemsetAsync(gh1, 0, (size_t)K * 16, stream);   // gh1 + gc1 + gc2

    ndcg_hist5<<<dim3(nb), dim3(1024), 0, stream>>>(sc, lb, gc1, gh1, gc2, n4, nb);
    ndcg_scan5<<<dim3(3), dim3(1024), 0, stream>>>(gc1, gc2, base1, base2, Dex, acc);
    ndcg_bucket<<<dim3(2 * K / 256), dim3(256), 0, stream>>>(base1, gh1, base2, Dex, acc);
    ndcg_fin<<<dim3(1), dim3(64), 0, stream>>>(acc, (float*)d_out);
}